// Round 1
// baseline (380.065 us; speedup 1.0000x reference)
//
#include <hip/hip_runtime.h>
#include <hip/hip_bf16.h>

// MoE layer, MI355X. B=16, C=64, H=W=128, E=8, TOPK=2.
// Inputs: x[B,C,H,W] f32, k[B,C,1,1] f32, Wg[C,E] f32, bg[E] f32,
//         W1[E,C,C] f32, b1[E,C] f32, W2[E,C,C] f32, b2[E,C] f32.
// Output: out[B,C,H,W] f32 = x + sum_{top2 experts} w_e * (W2_e @ gelu((W1_e@x + b1_e)*k) + b2_e)

#define BB 16
#define CC 64
#define EE 8
#define HWPX 16384

// ---------------- kernel 1: global average pool -> pooled[B*C] ----------------
__global__ __launch_bounds__(256) void pool_kernel(const float* __restrict__ x,
                                                   float* __restrict__ pooled) {
    int bc = blockIdx.x;  // 0..1023 = b*64+c
    const float* p = x + (size_t)bc * HWPX;
    float s = 0.f;
    for (int i = threadIdx.x; i < HWPX; i += 256) s += p[i];
    // wave (64-lane) reduce
    #pragma unroll
    for (int off = 32; off > 0; off >>= 1) s += __shfl_down(s, off);
    __shared__ float ls[4];
    if ((threadIdx.x & 63) == 0) ls[threadIdx.x >> 6] = s;
    __syncthreads();
    if (threadIdx.x == 0) {
        float t = (ls[0] + ls[1]) + (ls[2] + ls[3]);
        pooled[bc] = t * (1.0f / (float)HWPX);
    }
}

// ---------------- kernel 2: gate logits + softmax + top2 ----------------
__global__ void gate_kernel(const float* __restrict__ pooled,
                            const float* __restrict__ Wg,
                            const float* __restrict__ bg,
                            int* __restrict__ gidx, float* __restrict__ gw) {
    int b = threadIdx.x;
    if (b >= BB) return;
    float logits[EE];
    #pragma unroll
    for (int e = 0; e < EE; ++e) logits[e] = bg[e];
    for (int c = 0; c < CC; ++c) {
        float pv = pooled[b * CC + c];
        #pragma unroll
        for (int e = 0; e < EE; ++e) logits[e] = fmaf(pv, Wg[c * EE + e], logits[e]);
    }
    float m = logits[0];
    #pragma unroll
    for (int e = 1; e < EE; ++e) m = fmaxf(m, logits[e]);
    float w[EE]; float den = 0.f;
    #pragma unroll
    for (int e = 0; e < EE; ++e) { w[e] = expf(logits[e] - m); den += w[e]; }
    float inv = 1.0f / den;
    #pragma unroll
    for (int e = 0; e < EE; ++e) w[e] *= inv;
    // top-2, stable (lower index wins ties) like jax.lax.top_k
    int i0 = 0;
    #pragma unroll
    for (int e = 1; e < EE; ++e) if (w[e] > w[i0]) i0 = e;
    int i1 = -1;
    #pragma unroll
    for (int e = 0; e < EE; ++e) {
        if (e == i0) continue;
        if (i1 < 0 || w[e] > w[i1]) i1 = e;
    }
    gidx[b * 2 + 0] = i0;
    gidx[b * 2 + 1] = i1;
    gw[b * 2 + 0] = w[i0];
    gw[b * 2 + 1] = w[i1];
}

// ---------------- kernel 3: transpose W2 -> W2T[e][c_in][c_out] ----------------
__global__ __launch_bounds__(256) void w2t_kernel(const float* __restrict__ W2,
                                                  float* __restrict__ W2T) {
    int e = blockIdx.x;
    const float* src = W2 + (size_t)e * CC * CC;
    float* dst = W2T + (size_t)e * CC * CC;
    for (int i = threadIdx.x; i < CC * CC; i += 256) {
        int o = i >> 6, c = i & 63;
        dst[c * CC + o] = src[i];
    }
}

// ---------------- kernel 4: fused top-2 expert MLP + residual ----------------
__global__ __launch_bounds__(256) void moe_main(
    const float* __restrict__ x, const float* __restrict__ kvec,
    const float* __restrict__ W1, const float* __restrict__ b1,
    const float* __restrict__ W2T, const float* __restrict__ b2,
    const int* __restrict__ gidx, const float* __restrict__ gw,
    float* __restrict__ out) {
    int blk = blockIdx.x;                     // 0..1023
    int b = blk >> 6;                         // batch
    int p = ((blk & 63) << 8) + threadIdx.x;  // pixel 0..16383
    const float* xb = x + (size_t)b * CC * HWPX + p;

    float xv[CC], acc[CC];
    #pragma unroll
    for (int c = 0; c < CC; ++c) {
        xv[c] = xb[(size_t)c * HWPX];
        acc[c] = xv[c];
    }

    const float* kb = kvec + b * CC;

    #pragma unroll
    for (int s = 0; s < 2; ++s) {
        int e = __builtin_amdgcn_readfirstlane(gidx[b * 2 + s]);
        float wgt = gw[b * 2 + s];
        const float* W1e = W1 + (size_t)e * CC * CC;
        const float* W2Te = W2T + (size_t)e * CC * CC;
        const float* b1e = b1 + e * CC;
        const float* b2e = b2 + e * CC;

        // bias of second layer, gated
        #pragma unroll
        for (int o = 0; o < CC; ++o) acc[o] = fmaf(wgt, b2e[o], acc[o]);

        for (int o = 0; o < CC; ++o) {  // NOT unrolled: keep code size sane
            // h_o = gelu((W1[o,:] . xv + b1[o]) * k[b,o]); weights are wave-uniform -> scalar loads
            float a0 = 0.f, a1 = 0.f, a2 = 0.f, a3 = 0.f;
            #pragma unroll
            for (int c = 0; c < CC; c += 4) {
                a0 = fmaf(W1e[o * CC + c + 0], xv[c + 0], a0);
                a1 = fmaf(W1e[o * CC + c + 1], xv[c + 1], a1);
                a2 = fmaf(W1e[o * CC + c + 2], xv[c + 2], a2);
                a3 = fmaf(W1e[o * CC + c + 3], xv[c + 3], a3);
            }
            float a = ((a0 + a1) + (a2 + a3)) + b1e[o];
            float t = a * kb[o];
            // jax.nn.gelu approximate=True (tanh)
            float t3 = t * t * t;
            float u = 0.7978845608028654f * fmaf(0.044715f, t3, t);
            float g = 0.5f * t * (1.0f + tanhf(u));
            float hv = g * wgt;  // fold gate weight into h
            // acc[o2] += W2[o2][o] * h_o  (via transposed W2 row: contiguous scalar loads)
            #pragma unroll
            for (int o2 = 0; o2 < CC; ++o2)
                acc[o2] = fmaf(W2Te[o * CC + o2], hv, acc[o2]);
        }
    }

    float* ob = out + (size_t)b * CC * HWPX + p;
    #pragma unroll
    for (int c = 0; c < CC; ++c) ob[(size_t)c * HWPX] = acc[c];
}

extern "C" void kernel_launch(void* const* d_in, const int* in_sizes, int n_in,
                              void* d_out, int out_size, void* d_ws, size_t ws_size,
                              hipStream_t stream) {
    const float* x  = (const float*)d_in[0];
    const float* k  = (const float*)d_in[1];
    const float* Wg = (const float*)d_in[2];
    const float* bg = (const float*)d_in[3];
    const float* W1 = (const float*)d_in[4];
    const float* b1 = (const float*)d_in[5];
    const float* W2 = (const float*)d_in[6];
    const float* b2 = (const float*)d_in[7];
    float* out = (float*)d_out;

    // workspace layout
    float* pooled = (float*)d_ws;                          // 1024 floats
    int*   gidx   = (int*)((char*)d_ws + 4096);            // 32 ints
    float* gw     = (float*)((char*)d_ws + 4096 + 256);    // 32 floats
    float* W2T    = (float*)((char*)d_ws + 8192);          // 8*64*64 floats = 64 KiB

    pool_kernel<<<BB * CC, 256, 0, stream>>>(x, pooled);
    gate_kernel<<<1, 64, 0, stream>>>(pooled, Wg, bg, gidx, gw);
    w2t_kernel<<<EE, 256, 0, stream>>>(W2, W2T);
    moe_main<<<BB * 64, 256, 0, stream>>>(x, k, W1, b1, W2T, b2, gidx, gw, out);
}

// Round 3
// 70.685 us; speedup vs baseline: 5.3769x; 5.3769x over previous
//
#include <hip/hip_runtime.h>
#include <hip/hip_bf16.h>

// MoE layer, MI355X gfx950. B=16, C=64, H=W=128, E=8, TOPK=2.
// out = x + sum_{s in top2} w_s * (W2_e @ gelu((W1_e @ x + b1_e) * k) + b2_e)
// Strategy: top-2 only (4x FLOP cut vs reference), bf16 MFMA 16x16x32 for both
// 64x64 GEMMs, fused per (batch, 64-pixel tile) block.

#define BB 16
#define CC 64
#define EE 8
#define HWPX 16384

typedef __bf16 bf16x8 __attribute__((ext_vector_type(8)));
typedef float f32x4 __attribute__((ext_vector_type(4)));

__device__ __forceinline__ unsigned f2bf(float f) {
    unsigned u = __builtin_bit_cast(unsigned, f);
    return (u + 0x7fffu + ((u >> 16) & 1u)) >> 16;   // RNE
}

// ---------------- kernel 1: global average pool -> pooled[B*C] ----------------
__global__ __launch_bounds__(256) void pool_kernel(const float* __restrict__ x,
                                                   float* __restrict__ pooled) {
    int bc = blockIdx.x;  // b*64+c
    const float* p = x + (size_t)bc * HWPX;
    float s = 0.f;
    for (int i = threadIdx.x; i < HWPX; i += 256) s += p[i];
    #pragma unroll
    for (int off = 32; off > 0; off >>= 1) s += __shfl_down(s, off);
    __shared__ float ls[4];
    if ((threadIdx.x & 63) == 0) ls[threadIdx.x >> 6] = s;
    __syncthreads();
    if (threadIdx.x == 0) pooled[bc] = ((ls[0] + ls[1]) + (ls[2] + ls[3])) * (1.0f / (float)HWPX);
}

// ---------------- kernel 2: gate logits + softmax + top2 ----------------
__global__ void gate_kernel(const float* __restrict__ pooled,
                            const float* __restrict__ Wg,
                            const float* __restrict__ bg,
                            int* __restrict__ gidx, float* __restrict__ gw) {
    int b = threadIdx.x;
    if (b >= BB) return;
    float logits[EE];
    #pragma unroll
    for (int e = 0; e < EE; ++e) logits[e] = bg[e];
    for (int c = 0; c < CC; ++c) {
        float pv = pooled[b * CC + c];
        #pragma unroll
        for (int e = 0; e < EE; ++e) logits[e] = fmaf(pv, Wg[c * EE + e], logits[e]);
    }
    float m = logits[0];
    #pragma unroll
    for (int e = 1; e < EE; ++e) m = fmaxf(m, logits[e]);
    float w[EE]; float den = 0.f;
    #pragma unroll
    for (int e = 0; e < EE; ++e) { w[e] = expf(logits[e] - m); den += w[e]; }
    float inv = 1.0f / den;
    #pragma unroll
    for (int e = 0; e < EE; ++e) w[e] *= inv;
    int i0 = 0;
    #pragma unroll
    for (int e = 1; e < EE; ++e) if (w[e] > w[i0]) i0 = e;
    int i1 = -1;
    #pragma unroll
    for (int e = 0; e < EE; ++e) {
        if (e == i0) continue;
        if (i1 < 0 || w[e] > w[i1]) i1 = e;
    }
    gidx[b * 2 + 0] = i0; gidx[b * 2 + 1] = i1;
    gw[b * 2 + 0] = w[i0]; gw[b * 2 + 1] = w[i1];
}

// ---------------- kernel 3: convert W1,W2 to bf16 ----------------
__global__ __launch_bounds__(256) void wconv_kernel(const float* __restrict__ W1,
                                                    const float* __restrict__ W2,
                                                    unsigned short* __restrict__ W1b,
                                                    unsigned short* __restrict__ W2b) {
    int i = blockIdx.x * 256 + threadIdx.x;  // 0..32767
    if (i < EE * CC * CC) {
        W1b[i] = (unsigned short)f2bf(W1[i]);
        W2b[i] = (unsigned short)f2bf(W2[i]);
    }
}

// ---------------- kernel 4: fused top-2 expert MLP + residual (MFMA) ----------------
// Grid: 16 batches x 256 pixel-tiles (64 px each). Block: 256 thr = 4 waves.
// Wave w owns output rows 16w..16w+15 for all 64 px of the tile.
// LDS: xT[px][c] bf16, padded row stride 36 dwords (72 bf16) -> conflict-free
//      b128 fragment reads; hT same layout for the intermediate activation.
__global__ __launch_bounds__(256) void moe_main(
    const float* __restrict__ x, const float* __restrict__ kvec,
    const unsigned short* __restrict__ W1b, const float* __restrict__ b1,
    const unsigned short* __restrict__ W2b, const float* __restrict__ b2,
    const int* __restrict__ gidx, const float* __restrict__ gw,
    float* __restrict__ out) {

    __shared__ unsigned int xT32[64 * 36];
    __shared__ unsigned int hT32[64 * 36];

    const int blk = blockIdx.x;
    const int b = blk >> 8;            // batch
    const int p0 = (blk & 255) << 6;   // pixel tile start
    const int t = threadIdx.x;
    const int w = t >> 6;              // wave id 0..3
    const int l = t & 63;              // lane
    const int g = l >> 4;              // 16-lane group 0..3
    const int l15 = l & 15;

    // ---- stage x tile -> xT (transposed, bf16, packed pairs) ----
    {
        const int c0 = (t & 31) * 2;       // even channel
        const int px0 = (t >> 5) * 8;      // 8-pixel segment
        const float* r0 = x + ((size_t)(b * CC + c0)) * HWPX + p0 + px0;
        const float* r1 = r0 + HWPX;
        float4 A0 = *(const float4*)(r0);
        float4 A1 = *(const float4*)(r0 + 4);
        float4 B0 = *(const float4*)(r1);
        float4 B1 = *(const float4*)(r1 + 4);
        float av[8] = {A0.x, A0.y, A0.z, A0.w, A1.x, A1.y, A1.z, A1.w};
        float bv[8] = {B0.x, B0.y, B0.z, B0.w, B1.x, B1.y, B1.z, B1.w};
        #pragma unroll
        for (int i = 0; i < 8; ++i)
            xT32[(px0 + i) * 36 + (t & 31)] = (f2bf(bv[i]) << 16) | f2bf(av[i]);
    }
    __syncthreads();

    // ---- preload x B-fragments (reused by both experts' GEMM1) ----
    // B frag for col-tile cb, K-step ks: lane l holds x[k = 32ks+8g..+7][px = cb*16+l15]
    bf16x8 bx[4][2];
    #pragma unroll
    for (int cb = 0; cb < 4; ++cb)
        #pragma unroll
        for (int ks = 0; ks < 2; ++ks)
            bx[cb][ks] = *(const bf16x8*)&xT32[(cb * 16 + l15) * 36 + ks * 16 + g * 4];

    const float* kb = kvec + b * CC;
    const int arow = 16 * w + l15;           // A-fragment row (out channel)
    const int r0w = 16 * w + 4 * g;          // this lane's first D row

    f32x4 acc2[4];
    #pragma unroll
    for (int cb = 0; cb < 4; ++cb) acc2[cb] = (f32x4){0.f, 0.f, 0.f, 0.f};

    #pragma unroll
    for (int s = 0; s < 2; ++s) {
        const int e = __builtin_amdgcn_readfirstlane(gidx[b * 2 + s]);
        const float wgt = gw[b * 2 + s];
        const unsigned short* W1e = W1b + e * CC * CC;
        const unsigned short* W2e = W2b + e * CC * CC;
        const float* b1e = b1 + e * CC;
        const float* b2e = b2 + e * CC;

        // ---- GEMM1: h = W1_e @ x ----
        bf16x8 a1[2];
        #pragma unroll
        for (int ks = 0; ks < 2; ++ks)
            a1[ks] = *(const bf16x8*)(W1e + arow * CC + ks * 32 + g * 8);
        f32x4 hacc[4];
        #pragma unroll
        for (int cb = 0; cb < 4; ++cb) {
            hacc[cb] = (f32x4){0.f, 0.f, 0.f, 0.f};
            #pragma unroll
            for (int ks = 0; ks < 2; ++ks)
                hacc[cb] = __builtin_amdgcn_mfma_f32_16x16x32_bf16(a1[ks], bx[cb][ks], hacc[cb], 0, 0, 0);
        }

        // ---- bias + k-scale + gelu(tanh) + gate-weight, pack to hT ----
        float b1j[4], kkj[4];
        #pragma unroll
        for (int j = 0; j < 4; ++j) { b1j[j] = b1e[r0w + j]; kkj[j] = kb[r0w + j]; }

        __syncthreads();  // ensure prior GEMM2 reads of hT are done (s=1 case)

        #pragma unroll
        for (int cb = 0; cb < 4; ++cb) {
            unsigned hw[4];
            #pragma unroll
            for (int j = 0; j < 4; ++j) {
                float a = hacc[cb][j] + b1j[j];
                float tt = a * kkj[j];
                float t3 = tt * tt * tt;
                float u = 0.7978845608028654f * fmaf(0.044715f, t3, tt);
                float ex = __builtin_amdgcn_exp2f(2.8853900817779268f * u);  // e^{2u}
                float th = 1.f - 2.f * __builtin_amdgcn_rcpf(ex + 1.f);       // tanh(u)
                float gl = 0.5f * tt * (1.f + th);
                hw[j] = f2bf(gl * wgt);   // fold gate weight into h
            }
            const int px = cb * 16 + l15;
            hT32[px * 36 + 8 * w + 2 * g + 0] = (hw[1] << 16) | hw[0];
            hT32[px * 36 + 8 * w + 2 * g + 1] = (hw[3] << 16) | hw[2];
        }
        __syncthreads();

        // ---- GEMM2: acc2 += W2_e @ h (gate weight already in h) ----
        bf16x8 a2[2];
        #pragma unroll
        for (int ks = 0; ks < 2; ++ks)
            a2[ks] = *(const bf16x8*)(W2e + arow * CC + ks * 32 + g * 8);
        #pragma unroll
        for (int cb = 0; cb < 4; ++cb) {
            #pragma unroll
            for (int ks = 0; ks < 2; ++ks) {
                bf16x8 bh = *(const bf16x8*)&hT32[(cb * 16 + l15) * 36 + ks * 16 + g * 4];
                acc2[cb] = __builtin_amdgcn_mfma_f32_16x16x32_bf16(a2[ks], bh, acc2[cb], 0, 0, 0);
            }
        }

        // ---- gated b2 bias ----
        #pragma unroll
        for (int j = 0; j < 4; ++j) {
            float bb = wgt * b2e[r0w + j];
            #pragma unroll
            for (int cb = 0; cb < 4; ++cb) acc2[cb][j] += bb;
        }
    }

    // ---- epilogue: out = x + acc2 (exact f32 residual, x re-read is L2-warm) ----
    const float* xbase = x + (size_t)b * CC * HWPX + p0;
    float* obase = out + (size_t)b * CC * HWPX + p0;
    #pragma unroll
    for (int cb = 0; cb < 4; ++cb) {
        const int col = cb * 16 + l15;
        #pragma unroll
        for (int j = 0; j < 4; ++j) {
            size_t off = (size_t)(r0w + j) * HWPX + col;
            obase[off] = xbase[off] + acc2[cb][j];
        }
    }
}

extern "C" void kernel_launch(void* const* d_in, const int* in_sizes, int n_in,
                              void* d_out, int out_size, void* d_ws, size_t ws_size,
                              hipStream_t stream) {
    const float* x  = (const float*)d_in[0];
    const float* k  = (const float*)d_in[1];
    const float* Wg = (const float*)d_in[2];
    const float* bg = (const float*)d_in[3];
    const float* W1 = (const float*)d_in[4];
    const float* b1 = (const float*)d_in[5];
    const float* W2 = (const float*)d_in[6];
    const float* b2 = (const float*)d_in[7];
    float* out = (float*)d_out;

    // workspace layout
    float*          pooled = (float*)d_ws;                         // 4 KiB
    int*            gidx   = (int*)((char*)d_ws + 4096);           // 128 B
    float*          gw     = (float*)((char*)d_ws + 4096 + 128);   // 128 B
    unsigned short* W1b    = (unsigned short*)((char*)d_ws + 8192);            // 64 KiB
    unsigned short* W2b    = (unsigned short*)((char*)d_ws + 8192 + 65536);    // 64 KiB

    pool_kernel<<<BB * CC, 256, 0, stream>>>(x, pooled);
    gate_kernel<<<1, 64, 0, stream>>>(pooled, Wg, bg, gidx, gw);
    wconv_kernel<<<(EE * CC * CC + 255) / 256, 256, 0, stream>>>(W1, W2, W1b, W2b);
    moe_main<<<BB * 256, 256, 0, stream>>>(x, k, W1b, b1, W2b, b2, gidx, gw, out);
}

// Round 5
// 57.335 us; speedup vs baseline: 6.6289x; 1.2328x over previous
//
#include <hip/hip_runtime.h>
#include <hip/hip_bf16.h>

// MoE layer, MI355X gfx950. B=16, C=64, H=W=128, E=8, TOPK=2.
// out = x + sum_{s in top2} w_s * (W2_e @ gelu((W1_e @ x + b1_e) * k) + b2_e)
// bf16 MFMA 16x16x32 for both 64x64 GEMMs, fused per (batch, 64-px tile) block.

#define BB 16
#define CC 64
#define EE 8
#define HWPX 16384
#define LSTR 40   // LDS row stride in dwords (conflict-free hT b64 writes)

typedef __bf16 bf16x8 __attribute__((ext_vector_type(8)));
typedef float f32x4 __attribute__((ext_vector_type(4)));

__device__ __forceinline__ unsigned packbf2(float lo, float hi) {
    // compiler emits v_cvt_pk_bf16_f32 (RNE) for this
    __bf16 a = (__bf16)lo, b = (__bf16)hi;
    unsigned short ua = __builtin_bit_cast(unsigned short, a);
    unsigned short ub = __builtin_bit_cast(unsigned short, b);
    return ((unsigned)ub << 16) | (unsigned)ua;
}

// ---------------- kernel 1: global avg pool (blocks 0..1023) + W-conv (blocks 1024..1151) ----------------
__global__ __launch_bounds__(256) void pool_conv_kernel(
    const float* __restrict__ x, float* __restrict__ pooled,
    const float* __restrict__ W1, const float* __restrict__ W2,
    __bf16* __restrict__ W1b, __bf16* __restrict__ W2b) {
    int blk = blockIdx.x;
    if (blk < BB * CC) {
        const float4* p = (const float4*)(x + (size_t)blk * HWPX);
        float s = 0.f;
        for (int i = threadIdx.x; i < HWPX / 4; i += 256) {
            float4 v = p[i];
            s += (v.x + v.y) + (v.z + v.w);
        }
        #pragma unroll
        for (int off = 32; off > 0; off >>= 1) s += __shfl_down(s, off);
        __shared__ float ls[4];
        if ((threadIdx.x & 63) == 0) ls[threadIdx.x >> 6] = s;
        __syncthreads();
        if (threadIdx.x == 0) pooled[blk] = ((ls[0] + ls[1]) + (ls[2] + ls[3])) * (1.0f / (float)HWPX);
    } else {
        int i = (blk - BB * CC) * 256 + threadIdx.x;  // 0..32767
        W1b[i] = (__bf16)W1[i];
        W2b[i] = (__bf16)W2[i];
    }
}

// ---------------- kernel 2: gate logits + softmax + top2 ----------------
__global__ void gate_kernel(const float* __restrict__ pooled,
                            const float* __restrict__ Wg,
                            const float* __restrict__ bg,
                            int* __restrict__ gidx, float* __restrict__ gw) {
    int b = threadIdx.x;
    if (b >= BB) return;
    float logits[EE];
    #pragma unroll
    for (int e = 0; e < EE; ++e) logits[e] = bg[e];
    for (int c = 0; c < CC; ++c) {
        float pv = pooled[b * CC + c];
        #pragma unroll
        for (int e = 0; e < EE; ++e) logits[e] = fmaf(pv, Wg[c * EE + e], logits[e]);
    }
    float m = logits[0];
    #pragma unroll
    for (int e = 1; e < EE; ++e) m = fmaxf(m, logits[e]);
    float w[EE]; float den = 0.f;
    #pragma unroll
    for (int e = 0; e < EE; ++e) { w[e] = expf(logits[e] - m); den += w[e]; }
    float inv = 1.0f / den;
    #pragma unroll
    for (int e = 0; e < EE; ++e) w[e] *= inv;
    int i0 = 0;
    #pragma unroll
    for (int e = 1; e < EE; ++e) if (w[e] > w[i0]) i0 = e;
    int i1 = -1;
    #pragma unroll
    for (int e = 0; e < EE; ++e) {
        if (e == i0) continue;
        if (i1 < 0 || w[e] > w[i1]) i1 = e;
    }
    gidx[b * 2 + 0] = i0; gidx[b * 2 + 1] = i1;
    gw[b * 2 + 0] = w[i0]; gw[b * 2 + 1] = w[i1];
}

// ---------------- kernel 3: fused top-2 expert MLP + residual (MFMA) ----------------
// Grid: 16 batches x 256 pixel-tiles (64 px). Block: 256 thr = 4 waves.
// Wave w owns output channels 16w..16w+15 for all 64 px.
// LDS rows = pixels, cols = channels (bf16 pairs), stride LSTR=40 dwords.
__global__ __launch_bounds__(256) void moe_main(
    const float* __restrict__ x, const float* __restrict__ kvec,
    const __bf16* __restrict__ W1b, const float* __restrict__ b1,
    const __bf16* __restrict__ W2b, const float* __restrict__ b2,
    const int* __restrict__ gidx, const float* __restrict__ gw,
    float* __restrict__ out) {

    __shared__ unsigned int xT32[64 * LSTR];
    __shared__ unsigned int hT32[2][64 * LSTR];

    const int blk = blockIdx.x;
    const int b = blk >> 8;            // batch
    const int p0 = (blk & 255) << 6;   // pixel tile start
    const int t = threadIdx.x;
    const int w = t >> 6;              // wave id
    const int l = t & 63;              // lane
    const int g = l >> 4;              // 16-lane group
    const int l15 = l & 15;

    const int arow = 16 * w + l15;     // A-fragment row (out channel)
    const int r0w = 16 * w + 4 * g;    // this lane's first D row

    // ---- gate results + prefetch weight fragments & biases for BOTH experts ----
    const int e0 = __builtin_amdgcn_readfirstlane(gidx[b * 2 + 0]);
    const int e1 = __builtin_amdgcn_readfirstlane(gidx[b * 2 + 1]);
    const float wgt0 = gw[b * 2 + 0];
    const float wgt1 = gw[b * 2 + 1];

    bf16x8 a1f[2][2], a2f[2][2];
    #pragma unroll
    for (int ks = 0; ks < 2; ++ks) {
        a1f[0][ks] = *(const bf16x8*)(W1b + e0 * CC * CC + arow * CC + ks * 32 + g * 8);
        a1f[1][ks] = *(const bf16x8*)(W1b + e1 * CC * CC + arow * CC + ks * 32 + g * 8);
        a2f[0][ks] = *(const bf16x8*)(W2b + e0 * CC * CC + arow * CC + ks * 32 + g * 8);
        a2f[1][ks] = *(const bf16x8*)(W2b + e1 * CC * CC + arow * CC + ks * 32 + g * 8);
    }
    float b1j[2][4], b2j[2][4], kkj[4];
    #pragma unroll
    for (int j = 0; j < 4; ++j) {
        b1j[0][j] = b1[e0 * CC + r0w + j];
        b1j[1][j] = b1[e1 * CC + r0w + j];
        b2j[0][j] = b2[e0 * CC + r0w + j];
        b2j[1][j] = b2[e1 * CC + r0w + j];
        kkj[j]    = kvec[b * CC + r0w + j];
    }

    // ---- stage x tile -> xT (transposed, bf16 pairs) ----
    {
        const int c0 = (t & 31) * 2;       // even channel
        const int px0 = (t >> 5) * 8;      // 8-pixel segment
        const float* r0 = x + ((size_t)(b * CC + c0)) * HWPX + p0 + px0;
        const float* r1 = r0 + HWPX;
        float4 A0 = *(const float4*)(r0);
        float4 A1 = *(const float4*)(r0 + 4);
        float4 B0 = *(const float4*)(r1);
        float4 B1 = *(const float4*)(r1 + 4);
        float av[8] = {A0.x, A0.y, A0.z, A0.w, A1.x, A1.y, A1.z, A1.w};
        float bv[8] = {B0.x, B0.y, B0.z, B0.w, B1.x, B1.y, B1.z, B1.w};
        #pragma unroll
        for (int i = 0; i < 8; ++i)
            xT32[(px0 + i) * LSTR + (t & 31)] = packbf2(av[i], bv[i]);
    }
    __syncthreads();

    // ---- B-fragments of x (reused by both experts' GEMM1) ----
    bf16x8 bx[4][2];
    #pragma unroll
    for (int cb = 0; cb < 4; ++cb)
        #pragma unroll
        for (int ks = 0; ks < 2; ++ks)
            bx[cb][ks] = *(const bf16x8*)&xT32[(cb * 16 + l15) * LSTR + ks * 16 + g * 4];

    f32x4 acc2[4];
    #pragma unroll
    for (int cb = 0; cb < 4; ++cb) acc2[cb] = (f32x4){0.f, 0.f, 0.f, 0.f};

    // gelu sigmoid-form constants: gelu(t) = t * rcp(1 + exp2(t*(C1 + C2*t^2)))
    const float C1 = -2.302208239f;            // -2*log2(e)*0.7978845608
    const float C2 = -0.1029434f;              // C1 * 0.044715

    #pragma unroll
    for (int s = 0; s < 2; ++s) {
        const float wgt = s ? wgt1 : wgt0;

        // ---- GEMM1: h = W1_e @ x ----
        f32x4 hacc[4];
        #pragma unroll
        for (int cb = 0; cb < 4; ++cb) {
            hacc[cb] = (f32x4){0.f, 0.f, 0.f, 0.f};
            #pragma unroll
            for (int ks = 0; ks < 2; ++ks)
                hacc[cb] = __builtin_amdgcn_mfma_f32_16x16x32_bf16(a1f[s][ks], bx[cb][ks], hacc[cb], 0, 0, 0);
        }

        // ---- bias + k-scale + gelu + gate-weight -> hT[s] (b64 writes) ----
        #pragma unroll
        for (int cb = 0; cb < 4; ++cb) {
            float hv[4];
            #pragma unroll
            for (int j = 0; j < 4; ++j) {
                float a = hacc[cb][j] + b1j[s][j];
                float tt = a * kkj[j];
                float tt2 = tt * tt;
                float arg = tt * fmaf(C2, tt2, C1);
                float ex = __builtin_amdgcn_exp2f(arg);
                float r = __builtin_amdgcn_rcpf(ex + 1.f);
                hv[j] = (tt * wgt) * r;
            }
            const int px = cb * 16 + l15;
            uint2 pk;
            pk.x = packbf2(hv[0], hv[1]);
            pk.y = packbf2(hv[2], hv[3]);
            *(uint2*)&hT32[s][px * LSTR + 8 * w + 2 * g] = pk;
        }
        __syncthreads();

        // ---- GEMM2: acc2 += W2_e @ h (gate weight folded into h) ----
        #pragma unroll
        for (int cb = 0; cb < 4; ++cb) {
            #pragma unroll
            for (int ks = 0; ks < 2; ++ks) {
                bf16x8 bh = *(const bf16x8*)&hT32[s][(cb * 16 + l15) * LSTR + ks * 16 + g * 4];
                acc2[cb] = __builtin_amdgcn_mfma_f32_16x16x32_bf16(a2f[s][ks], bh, acc2[cb], 0, 0, 0);
            }
        }

        // ---- gated b2 bias ----
        #pragma unroll
        for (int j = 0; j < 4; ++j) {
            float bb = wgt * b2j[s][j];
            #pragma unroll
            for (int cb = 0; cb < 4; ++cb) acc2[cb][j] += bb;
        }
    }

    // ---- epilogue: out = x + acc2 (exact f32 residual; x re-read is L2-warm) ----
    const float* xbase = x + (size_t)b * CC * HWPX + p0;
    float* obase = out + (size_t)b * CC * HWPX + p0;
    #pragma unroll
    for (int cb = 0; cb < 4; ++cb) {
        const int col = cb * 16 + l15;
        #pragma unroll
        for (int j = 0; j < 4; ++j) {
            size_t off = (size_t)(r0w + j) * HWPX + col;
            __builtin_nontemporal_store(xbase[off] + acc2[cb][j], &obase[off]);
        }
    }
}

extern "C" void kernel_launch(void* const* d_in, const int* in_sizes, int n_in,
                              void* d_out, int out_size, void* d_ws, size_t ws_size,
                              hipStream_t stream) {
    const float* x  = (const float*)d_in[0];
    const float* k  = (const float*)d_in[1];
    const float* Wg = (const float*)d_in[2];
    const float* bg = (const float*)d_in[3];
    const float* W1 = (const float*)d_in[4];
    const float* b1 = (const float*)d_in[5];
    const float* W2 = (const float*)d_in[6];
    const float* b2 = (const float*)d_in[7];
    float* out = (float*)d_out;

    // workspace layout
    float*  pooled = (float*)d_ws;                          // 4 KiB
    int*    gidx   = (int*)((char*)d_ws + 4096);            // 128 B
    float*  gw     = (float*)((char*)d_ws + 4096 + 128);    // 128 B
    __bf16* W1b    = (__bf16*)((char*)d_ws + 8192);         // 64 KiB
    __bf16* W2b    = (__bf16*)((char*)d_ws + 8192 + 65536); // 64 KiB

    pool_conv_kernel<<<BB * CC + EE * CC * CC / 256, 256, 0, stream>>>(x, pooled, W1, W2, W1b, W2b);
    gate_kernel<<<1, 64, 0, stream>>>(pooled, Wg, bg, gidx, gw);
    moe_main<<<BB * 256, 256, 0, stream>>>(x, k, W1b, b1, W2b, b2, gidx, gw, out);
}

// Round 6
// 56.570 us; speedup vs baseline: 6.7185x; 1.0135x over previous
//
#include <hip/hip_runtime.h>
#include <hip/hip_bf16.h>

// MoE layer, MI355X gfx950. B=16, C=64, H=W=128, E=8, TOPK=2.
// out = x + sum_{s in top2} w_s * (W2_e @ gelu((W1_e @ x + b1_e) * k) + b2_e)
// bf16 MFMA 16x16x32 for both 64x64 GEMMs, fused per (batch, 64-px tile) block.

#define BB 16
#define CC 64
#define EE 8
#define HWPX 16384

typedef __bf16 bf16x8 __attribute__((ext_vector_type(8)));
typedef float f32x4 __attribute__((ext_vector_type(4)));

__device__ __forceinline__ unsigned packbf2(float lo, float hi) {
    // compiler emits v_cvt_pk_bf16_f32 (RNE) for this
    __bf16 a = (__bf16)lo, b = (__bf16)hi;
    unsigned short ua = __builtin_bit_cast(unsigned short, a);
    unsigned short ub = __builtin_bit_cast(unsigned short, b);
    return ((unsigned)ub << 16) | (unsigned)ua;
}

// XOR-swizzled dword index into a [64 px][32 dword] LDS tile.
// 16B-chunk XOR by (px&7) spreads the stride-128B columns across banks;
// same involution applied on write and read sides.
__device__ __forceinline__ int swz(int px, int d) {
    return px * 32 + ((d & ~3) ^ ((px & 7) << 2)) + (d & 3);
}

// ---------------- kernel 1: global avg pool (blocks 0..1023) + W-conv (blocks 1024..1151) ----------------
__global__ __launch_bounds__(256) void pool_conv_kernel(
    const float* __restrict__ x, float* __restrict__ pooled,
    const float* __restrict__ W1, const float* __restrict__ W2,
    __bf16* __restrict__ W1b, __bf16* __restrict__ W2b) {
    int blk = blockIdx.x;
    if (blk < BB * CC) {
        const float4* p = (const float4*)(x + (size_t)blk * HWPX);
        float s = 0.f;
        for (int i = threadIdx.x; i < HWPX / 4; i += 256) {
            float4 v = p[i];
            s += (v.x + v.y) + (v.z + v.w);
        }
        #pragma unroll
        for (int off = 32; off > 0; off >>= 1) s += __shfl_down(s, off);
        __shared__ float ls[4];
        if ((threadIdx.x & 63) == 0) ls[threadIdx.x >> 6] = s;
        __syncthreads();
        if (threadIdx.x == 0) pooled[blk] = ((ls[0] + ls[1]) + (ls[2] + ls[3])) * (1.0f / (float)HWPX);
    } else {
        int i = (blk - BB * CC) * 256 + threadIdx.x;  // 0..32767
        W1b[i] = (__bf16)W1[i];
        W2b[i] = (__bf16)W2[i];
    }
}

// ---------------- kernel 2: gate logits + softmax + top2 ----------------
__global__ void gate_kernel(const float* __restrict__ pooled,
                            const float* __restrict__ Wg,
                            const float* __restrict__ bg,
                            int* __restrict__ gidx, float* __restrict__ gw) {
    int b = threadIdx.x;
    if (b >= BB) return;
    float logits[EE];
    #pragma unroll
    for (int e = 0; e < EE; ++e) logits[e] = bg[e];
    for (int c = 0; c < CC; ++c) {
        float pv = pooled[b * CC + c];
        #pragma unroll
        for (int e = 0; e < EE; ++e) logits[e] = fmaf(pv, Wg[c * EE + e], logits[e]);
    }
    float m = logits[0];
    #pragma unroll
    for (int e = 1; e < EE; ++e) m = fmaxf(m, logits[e]);
    float w[EE]; float den = 0.f;
    #pragma unroll
    for (int e = 0; e < EE; ++e) { w[e] = expf(logits[e] - m); den += w[e]; }
    float inv = 1.0f / den;
    #pragma unroll
    for (int e = 0; e < EE; ++e) w[e] *= inv;
    int i0 = 0;
    #pragma unroll
    for (int e = 1; e < EE; ++e) if (w[e] > w[i0]) i0 = e;
    int i1 = -1;
    #pragma unroll
    for (int e = 0; e < EE; ++e) {
        if (e == i0) continue;
        if (i1 < 0 || w[e] > w[i1]) i1 = e;
    }
    gidx[b * 2 + 0] = i0; gidx[b * 2 + 1] = i1;
    gw[b * 2 + 0] = w[i0]; gw[b * 2 + 1] = w[i1];
}

// ---------------- kernel 3: fused top-2 expert MLP + residual (MFMA) ----------------
// Grid: 16 batches x 256 pixel-tiles (64 px). Block: 256 thr = 4 waves.
// Wave w owns output channels 16w..16w+15 for all 64 px.
// LDS: two 8 KiB [64 px][32 dword] XOR-swizzled tiles.
//   lds[0] = xT (bf16 pairs), later overlaid by hT1 (xT dead after bx loads).
//   lds[1] = hT0.
__global__ __launch_bounds__(256) void moe_main(
    const float* __restrict__ x, const float* __restrict__ kvec,
    const __bf16* __restrict__ W1b, const float* __restrict__ b1,
    const __bf16* __restrict__ W2b, const float* __restrict__ b2,
    const int* __restrict__ gidx, const float* __restrict__ gw,
    float* __restrict__ out) {

    __shared__ unsigned int lds[2][64 * 32];

    const int blk = blockIdx.x;
    const int b = blk >> 8;            // batch
    const int p0 = (blk & 255) << 6;   // pixel tile start
    const int t = threadIdx.x;
    const int w = t >> 6;              // wave id
    const int l = t & 63;              // lane
    const int g = l >> 4;              // 16-lane group
    const int l15 = l & 15;

    const int arow = 16 * w + l15;     // A-fragment row (out channel)
    const int r0w = 16 * w + 4 * g;    // this lane's first D row

    // ---- gate results + prefetch weight fragments & biases for BOTH experts ----
    const int e0 = __builtin_amdgcn_readfirstlane(gidx[b * 2 + 0]);
    const int e1 = __builtin_amdgcn_readfirstlane(gidx[b * 2 + 1]);
    const float wgt0 = gw[b * 2 + 0];
    const float wgt1 = gw[b * 2 + 1];

    bf16x8 a1f[2][2];
    #pragma unroll
    for (int ks = 0; ks < 2; ++ks) {
        a1f[0][ks] = *(const bf16x8*)(W1b + e0 * CC * CC + arow * CC + ks * 32 + g * 8);
        a1f[1][ks] = *(const bf16x8*)(W1b + e1 * CC * CC + arow * CC + ks * 32 + g * 8);
    }
    float b1j[2][4], b2j[2][4], kkj[4];
    #pragma unroll
    for (int j = 0; j < 4; ++j) {
        b1j[0][j] = b1[e0 * CC + r0w + j];
        b1j[1][j] = b1[e1 * CC + r0w + j];
        b2j[0][j] = b2[e0 * CC + r0w + j];
        b2j[1][j] = b2[e1 * CC + r0w + j];
        kkj[j]    = kvec[b * CC + r0w + j];
    }

    // ---- stage x tile -> lds[0] (transposed, bf16 pairs, swizzled) ----
    {
        const int c0 = (t & 31);           // channel-pair dword column
        const int px0 = (t >> 5) * 8;      // 8-pixel segment
        const float* r0 = x + ((size_t)(b * CC + c0 * 2)) * HWPX + p0 + px0;
        const float* r1 = r0 + HWPX;
        float4 A0 = *(const float4*)(r0);
        float4 A1 = *(const float4*)(r0 + 4);
        float4 B0 = *(const float4*)(r1);
        float4 B1 = *(const float4*)(r1 + 4);
        float av[8] = {A0.x, A0.y, A0.z, A0.w, A1.x, A1.y, A1.z, A1.w};
        float bv[8] = {B0.x, B0.y, B0.z, B0.w, B1.x, B1.y, B1.z, B1.w};
        #pragma unroll
        for (int i = 0; i < 8; ++i)
            lds[0][swz(px0 + i, c0)] = packbf2(av[i], bv[i]);
    }
    __syncthreads();   // bar1: xT staged

    // ---- B-fragments of x (reused by both experts' GEMM1); after this xT is dead ----
    bf16x8 bx[4][2];
    #pragma unroll
    for (int cb = 0; cb < 4; ++cb)
        #pragma unroll
        for (int ks = 0; ks < 2; ++ks)
            bx[cb][ks] = *(const bf16x8*)&lds[0][swz(cb * 16 + l15, ks * 16 + g * 4)];

    // gelu sigmoid-form constants: gelu(t) = t * rcp(1 + exp2(t*(C1 + C2*t^2)))
    const float C1 = -2.302208239f;            // -2*log2(e)*0.7978845608
    const float C2 = -0.1029434f;              // C1 * 0.044715

    // ---- GEMM1 for both experts (16 independent MFMA chains) ----
    f32x4 h0[4], h1[4];
    #pragma unroll
    for (int cb = 0; cb < 4; ++cb) {
        h0[cb] = (f32x4){0.f, 0.f, 0.f, 0.f};
        h1[cb] = (f32x4){0.f, 0.f, 0.f, 0.f};
        #pragma unroll
        for (int ks = 0; ks < 2; ++ks) {
            h0[cb] = __builtin_amdgcn_mfma_f32_16x16x32_bf16(a1f[0][ks], bx[cb][ks], h0[cb], 0, 0, 0);
            h1[cb] = __builtin_amdgcn_mfma_f32_16x16x32_bf16(a1f[1][ks], bx[cb][ks], h1[cb], 0, 0, 0);
        }
    }

    // ---- gelu + pack both experts (gate weight folded in) ----
    uint2 p0k[4], p1k[4];
    #pragma unroll
    for (int cb = 0; cb < 4; ++cb) {
        float hv0[4], hv1[4];
        #pragma unroll
        for (int j = 0; j < 4; ++j) {
            float a0 = h0[cb][j] + b1j[0][j];
            float t0 = a0 * kkj[j];
            float ex0 = __builtin_amdgcn_exp2f(t0 * fmaf(C2, t0 * t0, C1));
            hv0[j] = (t0 * wgt0) * __builtin_amdgcn_rcpf(ex0 + 1.f);
            float a1 = h1[cb][j] + b1j[1][j];
            float t1 = a1 * kkj[j];
            float ex1 = __builtin_amdgcn_exp2f(t1 * fmaf(C2, t1 * t1, C1));
            hv1[j] = (t1 * wgt1) * __builtin_amdgcn_rcpf(ex1 + 1.f);
        }
        p0k[cb].x = packbf2(hv0[0], hv0[1]);
        p0k[cb].y = packbf2(hv0[2], hv0[3]);
        p1k[cb].x = packbf2(hv1[0], hv1[1]);
        p1k[cb].y = packbf2(hv1[2], hv1[3]);
    }

    // ---- write hT0 (lds[1], no overlap with xT) ----
    #pragma unroll
    for (int cb = 0; cb < 4; ++cb)
        *(uint2*)&lds[1][swz(cb * 16 + l15, 8 * w + 2 * g)] = p0k[cb];

    // load W2 A-fragments for both experts (L2-hot)
    bf16x8 a2f[2][2];
    #pragma unroll
    for (int ks = 0; ks < 2; ++ks) {
        a2f[0][ks] = *(const bf16x8*)(W2b + e0 * CC * CC + arow * CC + ks * 32 + g * 8);
        a2f[1][ks] = *(const bf16x8*)(W2b + e1 * CC * CC + arow * CC + ks * 32 + g * 8);
    }

    __syncthreads();   // bar2: all xT reads done, hT0 visible

    // ---- write hT1 into lds[0] (overlay on dead xT) ----
    #pragma unroll
    for (int cb = 0; cb < 4; ++cb)
        *(uint2*)&lds[0][swz(cb * 16 + l15, 8 * w + 2 * g)] = p1k[cb];

    // ---- prefetch epilogue x (L2/L3-warm) ----
    const float* xbase = x + (size_t)b * CC * HWPX + p0;
    float xp[4][4];
    #pragma unroll
    for (int cb = 0; cb < 4; ++cb)
        #pragma unroll
        for (int j = 0; j < 4; ++j)
            xp[cb][j] = xbase[(size_t)(r0w + j) * HWPX + cb * 16 + l15];

    f32x4 acc2[4];
    #pragma unroll
    for (int cb = 0; cb < 4; ++cb) acc2[cb] = (f32x4){0.f, 0.f, 0.f, 0.f};

    // ---- GEMM2 expert0 (reads hT0; overlaps hT1 ds_writes landing) ----
    #pragma unroll
    for (int cb = 0; cb < 4; ++cb) {
        #pragma unroll
        for (int ks = 0; ks < 2; ++ks) {
            bf16x8 bh = *(const bf16x8*)&lds[1][swz(cb * 16 + l15, ks * 16 + g * 4)];
            acc2[cb] = __builtin_amdgcn_mfma_f32_16x16x32_bf16(a2f[0][ks], bh, acc2[cb], 0, 0, 0);
        }
    }

    __syncthreads();   // bar3: hT1 visible

    // ---- GEMM2 expert1 ----
    #pragma unroll
    for (int cb = 0; cb < 4; ++cb) {
        #pragma unroll
        for (int ks = 0; ks < 2; ++ks) {
            bf16x8 bh = *(const bf16x8*)&lds[0][swz(cb * 16 + l15, ks * 16 + g * 4)];
            acc2[cb] = __builtin_amdgcn_mfma_f32_16x16x32_bf16(a2f[1][ks], bh, acc2[cb], 0, 0, 0);
        }
    }

    // ---- epilogue: out = x + acc2 + gated b2 (plain stores; L2 merges lines) ----
    float bsum[4];
    #pragma unroll
    for (int j = 0; j < 4; ++j)
        bsum[j] = fmaf(wgt0, b2j[0][j], wgt1 * b2j[1][j]);

    float* obase = out + (size_t)b * CC * HWPX + p0;
    #pragma unroll
    for (int cb = 0; cb < 4; ++cb) {
        const int col = cb * 16 + l15;
        #pragma unroll
        for (int j = 0; j < 4; ++j) {
            size_t off = (size_t)(r0w + j) * HWPX + col;
            obase[off] = xp[cb][j] + (acc2[cb][j] + bsum[j]);
        }
    }
}

extern "C" void kernel_launch(void* const* d_in, const int* in_sizes, int n_in,
                              void* d_out, int out_size, void* d_ws, size_t ws_size,
                              hipStream_t stream) {
    const float* x  = (const float*)d_in[0];
    const float* k  = (const float*)d_in[1];
    const float* Wg = (const float*)d_in[2];
    const float* bg = (const float*)d_in[3];
    const float* W1 = (const float*)d_in[4];
    const float* b1 = (const float*)d_in[5];
    const float* W2 = (const float*)d_in[6];
    const float* b2 = (const float*)d_in[7];
    float* out = (float*)d_out;

    // workspace layout
    float*  pooled = (float*)d_ws;                          // 4 KiB
    int*    gidx   = (int*)((char*)d_ws + 4096);            // 128 B
    float*  gw     = (float*)((char*)d_ws + 4096 + 128);    // 128 B
    __bf16* W1b    = (__bf16*)((char*)d_ws + 8192);         // 64 KiB
    __bf16* W2b    = (__bf16*)((char*)d_ws + 8192 + 65536); // 64 KiB

    pool_conv_kernel<<<BB * CC + EE * CC * CC / 256, 256, 0, stream>>>(x, pooled, W1, W2, W1b, W2b);
    gate_kernel<<<1, 64, 0, stream>>>(pooled, Wg, bg, gidx, gw);
    moe_main<<<BB * 256, 256, 0, stream>>>(x, k, W1b, b1, W2b, b2, gidx, gw, out);
}

// Round 7
// 51.154 us; speedup vs baseline: 7.4298x; 1.1059x over previous
//
#include <hip/hip_runtime.h>
#include <hip/hip_bf16.h>

// MoE layer, MI355X gfx950. B=16, C=64, H=W=128, E=8, TOPK=2.
// out = x + sum_{s in top2} w_s * (W2_e @ gelu((W1_e @ x + b1_e) * k) + b2_e)
// bf16 MFMA 16x16x32; fused per (batch, 256-px super-tile) block, 4 pipelined
// 64-px tiles per block; residual kept in registers (x read exactly once).

#define BB 16
#define CC 64
#define EE 8
#define HWPX 16384
#define NT 4

typedef __bf16 bf16x8 __attribute__((ext_vector_type(8)));
typedef float f32x4 __attribute__((ext_vector_type(4)));

__device__ __forceinline__ unsigned packbf2(float lo, float hi) {
    // compiler emits v_cvt_pk_bf16_f32 (RNE)
    __bf16 a = (__bf16)lo, b = (__bf16)hi;
    unsigned short ua = __builtin_bit_cast(unsigned short, a);
    unsigned short ub = __builtin_bit_cast(unsigned short, b);
    return ((unsigned)ub << 16) | (unsigned)ua;
}

// XOR-swizzled dword index into a [64 px][32 dword] LDS tile.
// Same involution on write and read; 16B chunks XORed by (px&7).
__device__ __forceinline__ int swz(int px, int d) {
    return px * 32 + ((d & ~3) ^ ((px & 7) << 2)) + (d & 3);
}

// ---------------- kernel 1: global avg pool (blocks 0..1023) + W-conv (blocks 1024..1151) ----------------
__global__ __launch_bounds__(256) void pool_conv_kernel(
    const float* __restrict__ x, float* __restrict__ pooled,
    const float* __restrict__ W1, const float* __restrict__ W2,
    __bf16* __restrict__ W1b, __bf16* __restrict__ W2b) {
    int blk = blockIdx.x;
    if (blk < BB * CC) {
        const float4* p = (const float4*)(x + (size_t)blk * HWPX);
        float s = 0.f;
        for (int i = threadIdx.x; i < HWPX / 4; i += 256) {
            float4 v = p[i];
            s += (v.x + v.y) + (v.z + v.w);
        }
        #pragma unroll
        for (int off = 32; off > 0; off >>= 1) s += __shfl_down(s, off);
        __shared__ float ls[4];
        if ((threadIdx.x & 63) == 0) ls[threadIdx.x >> 6] = s;
        __syncthreads();
        if (threadIdx.x == 0) pooled[blk] = ((ls[0] + ls[1]) + (ls[2] + ls[3])) * (1.0f / (float)HWPX);
    } else {
        int i = (blk - BB * CC) * 256 + threadIdx.x;  // 0..32767
        W1b[i] = (__bf16)W1[i];
        W2b[i] = (__bf16)W2[i];
    }
}

// ---------------- kernel 2: gate logits + softmax + top2 ----------------
__global__ void gate_kernel(const float* __restrict__ pooled,
                            const float* __restrict__ Wg,
                            const float* __restrict__ bg,
                            int* __restrict__ gidx, float* __restrict__ gw) {
    int b = threadIdx.x;
    if (b >= BB) return;
    float logits[EE];
    #pragma unroll
    for (int e = 0; e < EE; ++e) logits[e] = bg[e];
    for (int c = 0; c < CC; ++c) {
        float pv = pooled[b * CC + c];
        #pragma unroll
        for (int e = 0; e < EE; ++e) logits[e] = fmaf(pv, Wg[c * EE + e], logits[e]);
    }
    float m = logits[0];
    #pragma unroll
    for (int e = 1; e < EE; ++e) m = fmaxf(m, logits[e]);
    float w[EE]; float den = 0.f;
    #pragma unroll
    for (int e = 0; e < EE; ++e) { w[e] = expf(logits[e] - m); den += w[e]; }
    float inv = 1.0f / den;
    #pragma unroll
    for (int e = 0; e < EE; ++e) w[e] *= inv;
    int i0 = 0;
    #pragma unroll
    for (int e = 1; e < EE; ++e) if (w[e] > w[i0]) i0 = e;
    int i1 = -1;
    #pragma unroll
    for (int e = 0; e < EE; ++e) {
        if (e == i0) continue;
        if (i1 < 0 || w[e] > w[i1]) i1 = e;
    }
    gidx[b * 2 + 0] = i0; gidx[b * 2 + 1] = i1;
    gw[b * 2 + 0] = w[i0]; gw[b * 2 + 1] = w[i1];
}

// ---------------- kernel 3: fused top-2 expert MLP + residual (MFMA, pipelined) ----------------
// Grid: 16 batches x 64 super-tiles (256 px). Block: 256 thr = 4 waves, NT=4 tiles.
// Thread (w,g,l15) owns channels r0w..r0w+3 x pixels {16cb+l15} of each tile:
// loads them once (residual regs), stages them to LDS bf16, stores the output.
// LDS: two 8 KiB [64px][32dw] swizzled buffers, roles alternate per tile.
__global__ __launch_bounds__(256) void moe_main(
    const float* __restrict__ x, const float* __restrict__ kvec,
    const __bf16* __restrict__ W1b, const float* __restrict__ b1,
    const __bf16* __restrict__ W2b, const float* __restrict__ b2,
    const int* __restrict__ gidx, const float* __restrict__ gw,
    float* __restrict__ out) {

    __shared__ unsigned int LA[64 * 32];
    __shared__ unsigned int LB[64 * 32];

    const int blk = blockIdx.x;
    const int b = blk >> 6;            // batch
    const int P0 = (blk & 63) << 8;    // super-tile base pixel
    const int t = threadIdx.x;
    const int w = t >> 6;              // wave id
    const int l = t & 63;
    const int g = l >> 4;              // 16-lane group
    const int l15 = l & 15;

    const int arow = 16 * w + l15;     // A-fragment row (out channel)
    const int r0w = 16 * w + 4 * g;    // this lane's first owned channel
    const int d0 = 8 * w + 2 * g;      // LDS dword column for ch pair base

    // ---- gate results ----
    const int e0 = __builtin_amdgcn_readfirstlane(gidx[b * 2 + 0]);
    const int e1 = __builtin_amdgcn_readfirstlane(gidx[b * 2 + 1]);
    const float wgt0 = gw[b * 2 + 0];
    const float wgt1 = gw[b * 2 + 1];

    const float* xb = x + b * CC * HWPX;   // int offsets from here (<64MB)
    float* ob = out + b * CC * HWPX;
    const int obase = r0w * HWPX + P0 + l15;

    // ---- tile-0 x loads (residual + staging source) ----
    float xc[16];
    #pragma unroll
    for (int cb = 0; cb < 4; ++cb)
        #pragma unroll
        for (int j = 0; j < 4; ++j)
            xc[cb * 4 + j] = xb[obase + j * HWPX + cb * 16];

    // ---- weights (held for whole block) + biases ----
    bf16x8 a1f[2][2], a2f[2][2];
    #pragma unroll
    for (int ks = 0; ks < 2; ++ks) {
        a1f[0][ks] = *(const bf16x8*)(W1b + e0 * CC * CC + arow * CC + ks * 32 + g * 8);
        a1f[1][ks] = *(const bf16x8*)(W1b + e1 * CC * CC + arow * CC + ks * 32 + g * 8);
        a2f[0][ks] = *(const bf16x8*)(W2b + e0 * CC * CC + arow * CC + ks * 32 + g * 8);
        a2f[1][ks] = *(const bf16x8*)(W2b + e1 * CC * CC + arow * CC + ks * 32 + g * 8);
    }
    const f32x4 b1v0 = *(const f32x4*)(b1 + e0 * CC + r0w);
    const f32x4 b1v1 = *(const f32x4*)(b1 + e1 * CC + r0w);
    const f32x4 b2v0 = *(const f32x4*)(b2 + e0 * CC + r0w);
    const f32x4 b2v1 = *(const f32x4*)(b2 + e1 * CC + r0w);
    const f32x4 kk   = *(const f32x4*)(kvec + b * CC + r0w);

    float bsum[4];
    #pragma unroll
    for (int j = 0; j < 4; ++j) bsum[j] = fmaf(wgt0, b2v0[j], wgt1 * b2v1[j]);

    // gelu sigmoid-form constants: gelu(t) = t * rcp(1 + exp2(t*(C1 + C2*t^2)))
    const float C1 = -2.302208239f;    // -2*log2(e)*0.7978845608
    const float C2 = -0.1029434f;      // C1 * 0.044715

    // ---- stage tile 0 -> LA ----
    #pragma unroll
    for (int cb = 0; cb < 4; ++cb) {
        uint2 pk;
        pk.x = packbf2(xc[cb * 4 + 0], xc[cb * 4 + 1]);
        pk.y = packbf2(xc[cb * 4 + 2], xc[cb * 4 + 3]);
        *(uint2*)&LA[swz(cb * 16 + l15, d0)] = pk;
    }
    __syncthreads();   // tile 0 xT visible

    #pragma unroll
    for (int it = 0; it < NT; ++it) {
        unsigned int* XT = (it & 1) ? LB : LA;   // xT, later hT1 overlay
        unsigned int* H0 = (it & 1) ? LA : LB;   // hT0, later next xT

        // ---- prefetch next tile's x (lands under GEMM1/gelu/GEMM2) ----
        float xn[16];
        if (it < NT - 1) {
            #pragma unroll
            for (int cb = 0; cb < 4; ++cb)
                #pragma unroll
                for (int j = 0; j < 4; ++j)
                    xn[cb * 4 + j] = xb[obase + (it + 1) * 64 + j * HWPX + cb * 16];
        }

        // ---- x B-fragments ----
        bf16x8 bx[4][2];
        #pragma unroll
        for (int cb = 0; cb < 4; ++cb)
            #pragma unroll
            for (int ks = 0; ks < 2; ++ks)
                bx[cb][ks] = *(const bf16x8*)&XT[swz(cb * 16 + l15, ks * 16 + g * 4)];

        // ---- GEMM1 both experts ----
        f32x4 h0[4], h1[4];
        #pragma unroll
        for (int cb = 0; cb < 4; ++cb) {
            h0[cb] = (f32x4){0.f, 0.f, 0.f, 0.f};
            h1[cb] = (f32x4){0.f, 0.f, 0.f, 0.f};
            #pragma unroll
            for (int ks = 0; ks < 2; ++ks) {
                h0[cb] = __builtin_amdgcn_mfma_f32_16x16x32_bf16(a1f[0][ks], bx[cb][ks], h0[cb], 0, 0, 0);
                h1[cb] = __builtin_amdgcn_mfma_f32_16x16x32_bf16(a1f[1][ks], bx[cb][ks], h1[cb], 0, 0, 0);
            }
        }

        // ---- gelu + pack (gate weights folded in) ----
        uint2 p0k[4], p1k[4];
        #pragma unroll
        for (int cb = 0; cb < 4; ++cb) {
            float hv0[4], hv1[4];
            #pragma unroll
            for (int j = 0; j < 4; ++j) {
                float t0 = (h0[cb][j] + b1v0[j]) * kk[j];
                float ex0 = __builtin_amdgcn_exp2f(t0 * fmaf(C2, t0 * t0, C1));
                hv0[j] = (t0 * wgt0) * __builtin_amdgcn_rcpf(ex0 + 1.f);
                float t1 = (h1[cb][j] + b1v1[j]) * kk[j];
                float ex1 = __builtin_amdgcn_exp2f(t1 * fmaf(C2, t1 * t1, C1));
                hv1[j] = (t1 * wgt1) * __builtin_amdgcn_rcpf(ex1 + 1.f);
            }
            p0k[cb].x = packbf2(hv0[0], hv0[1]);
            p0k[cb].y = packbf2(hv0[2], hv0[3]);
            p1k[cb].x = packbf2(hv1[0], hv1[1]);
            p1k[cb].y = packbf2(hv1[2], hv1[3]);
        }

        // ---- hT0 -> H0 ----
        #pragma unroll
        for (int cb = 0; cb < 4; ++cb)
            *(uint2*)&H0[swz(cb * 16 + l15, d0)] = p0k[cb];
        __syncthreads();   // bx reads of XT done + hT0 visible

        // ---- hT1 overlays XT ----
        #pragma unroll
        for (int cb = 0; cb < 4; ++cb)
            *(uint2*)&XT[swz(cb * 16 + l15, d0)] = p1k[cb];

        // ---- GEMM2 expert0 (reads H0) ----
        f32x4 acc[4];
        #pragma unroll
        for (int cb = 0; cb < 4; ++cb) {
            acc[cb] = (f32x4){0.f, 0.f, 0.f, 0.f};
            #pragma unroll
            for (int ks = 0; ks < 2; ++ks) {
                bf16x8 bh = *(const bf16x8*)&H0[swz(cb * 16 + l15, ks * 16 + g * 4)];
                acc[cb] = __builtin_amdgcn_mfma_f32_16x16x32_bf16(a2f[0][ks], bh, acc[cb], 0, 0, 0);
            }
        }
        __syncthreads();   // e0 reads of H0 done + hT1 visible

        // ---- next tile's xT into H0 (now dead) ----
        if (it < NT - 1) {
            #pragma unroll
            for (int cb = 0; cb < 4; ++cb) {
                uint2 pk;
                pk.x = packbf2(xn[cb * 4 + 0], xn[cb * 4 + 1]);
                pk.y = packbf2(xn[cb * 4 + 2], xn[cb * 4 + 3]);
                *(uint2*)&H0[swz(cb * 16 + l15, d0)] = pk;
            }
        }

        // ---- GEMM2 expert1 (reads hT1 in XT) ----
        #pragma unroll
        for (int cb = 0; cb < 4; ++cb) {
            #pragma unroll
            for (int ks = 0; ks < 2; ++ks) {
                bf16x8 bh = *(const bf16x8*)&XT[swz(cb * 16 + l15, ks * 16 + g * 4)];
                acc[cb] = __builtin_amdgcn_mfma_f32_16x16x32_bf16(a2f[1][ks], bh, acc[cb], 0, 0, 0);
            }
        }

        // ---- epilogue: out = x + acc + gated b2 (residual from registers) ----
        #pragma unroll
        for (int cb = 0; cb < 4; ++cb)
            #pragma unroll
            for (int j = 0; j < 4; ++j)
                ob[obase + it * 64 + j * HWPX + cb * 16] = xc[cb * 4 + j] + (acc[cb][j] + bsum[j]);

        if (it < NT - 1) {
            #pragma unroll
            for (int i = 0; i < 16; ++i) xc[i] = xn[i];
            __syncthreads();   // next xT visible
        }
    }
}

extern "C" void kernel_launch(void* const* d_in, const int* in_sizes, int n_in,
                              void* d_out, int out_size, void* d_ws, size_t ws_size,
                              hipStream_t stream) {
    const float* x  = (const float*)d_in[0];
    const float* k  = (const float*)d_in[1];
    const float* Wg = (const float*)d_in[2];
    const float* bg = (const float*)d_in[3];
    const float* W1 = (const float*)d_in[4];
    const float* b1 = (const float*)d_in[5];
    const float* W2 = (const float*)d_in[6];
    const float* b2 = (const float*)d_in[7];
    float* out = (float*)d_out;

    // workspace layout
    float*  pooled = (float*)d_ws;                          // 4 KiB
    int*    gidx   = (int*)((char*)d_ws + 4096);            // 128 B
    float*  gw     = (float*)((char*)d_ws + 4096 + 128);    // 128 B
    __bf16* W1b    = (__bf16*)((char*)d_ws + 8192);         // 64 KiB
    __bf16* W2b    = (__bf16*)((char*)d_ws + 8192 + 65536); // 64 KiB

    pool_conv_kernel<<<BB * CC + EE * CC * CC / 256, 256, 0, stream>>>(x, pooled, W1, W2, W1b, W2b);
    gate_kernel<<<1, 64, 0, stream>>>(pooled, Wg, bg, gidx, gw);
    moe_main<<<BB * 64, 256, 0, stream>>>(x, k, W1b, b1, W2b, b2, gidx, gw, out);
}